// Round 1
// baseline (13820.386 us; speedup 1.0000x reference)
//
#include <hip/hip_runtime.h>

// ContextLSTM: B=128, T=512, I=1024, H=1024, C=512
// out tuple: out[B,T,H], h_f[B,H], c_f[B,H]  (fp32, concatenated in d_out)

typedef __attribute__((ext_vector_type(8))) short short8;   // 8 x bf16 (4 VGPRs)
typedef __attribute__((ext_vector_type(4))) float floatx4;  // MFMA accumulator
typedef unsigned short u16;
typedef unsigned int u32;

#define Bsz 128
#define Tsz 512
#define Isz 1024
#define Hsz 1024
#define G4  4096   // 4*H

__device__ __forceinline__ u16 f2bf(float f) {
    union { float f; u32 u; } v; v.f = f;
    u32 r = (v.u + 0x7fffu + ((v.u >> 16) & 1u)) >> 16;
    return (u16)r;
}
__device__ __forceinline__ float bf2f(u16 h) {
    union { u32 u; float f; } v; v.u = ((u32)h) << 16;
    return v.f;
}

// hT fragment layout for h[b][u]:  bt=b>>4, kt=u>>5, lane=(b&15)+(((u>>3)&3)<<4), j=u&7
// off = ((bt*32+kt)*64+lane)*8 + j   (u16 units; one state = 131072 u16 = 256 KB)
__device__ __forceinline__ int ht_off(int b, int u) {
    return (((((b >> 4) * 32 + (u >> 5)) << 6) + (b & 15) + (((u >> 3) & 3) << 4)) << 3) + (u & 7);
}

// ---------------------------------------------------------------------------
// Cast Wi and Wh to bf16 (each 4H x K = 4194304 elements)
__global__ void k_cast_w(const float* __restrict__ Wi, const float* __restrict__ Wh,
                         u16* __restrict__ WiB, u16* __restrict__ WhB) {
    int i = blockIdx.x * 256 + threadIdx.x;   // grid covers 4194304
    WiB[i] = f2bf(Wi[i]);
    WhB[i] = f2bf(Wh[i]);
}

// h0 -> hT fragment layout (state 0)
__global__ void k_state(const float* __restrict__ h0, u16* __restrict__ hT) {
    int i = blockIdx.x * 256 + threadIdx.x;   // 131072
    int b = i >> 10, u = i & 1023;
    hT[ht_off(b, u)] = f2bf(h0[i]);
}

// zero step-barrier counters (32768 u32 = 128 KB, 64 B stride entries)
__global__ void k_zero(u32* __restrict__ bar) {
    bar[blockIdx.x * 256 + threadIdx.x] = 0;
}

// ctxg[b,g] = ctx[b,:] . Wc[g,:] + bi[g] + bh[g] + bc[g]   (fp32, [B,4H])
__global__ void k_ctxg(const float* __restrict__ ctx, const float* __restrict__ Wc,
                       const float* __restrict__ bi, const float* __restrict__ bh,
                       const float* __restrict__ bc, float* __restrict__ ctxg) {
    int bid = blockIdx.x;               // 128*16 blocks
    int b = bid >> 4;
    int g = (bid & 15) * 256 + threadIdx.x;
    const float* wr = Wc + (long)g * 512;
    const float* cr = ctx + (long)b * 512;
    float s = 0.f;
    #pragma unroll 4
    for (int k = 0; k < 512; k += 4) {
        float4 w = *(const float4*)&wr[k];
        float4 c = *(const float4*)&cr[k];
        s += w.x * c.x + w.y * c.y + w.z * c.z + w.w * c.w;
    }
    ctxg[(long)b * G4 + g] = s + bi[g] + bh[g] + bc[g];
}

// ---------------------------------------------------------------------------
// Phase A: pre2 tiled layout: region (t, mb, nb) of [32 rows(batch) x 64 cols] u16,
// col = gate*16 + unit-within-16.  pre2 idx = (((t*4+mb)*64+nb)*2048 + brow*64 + col)
__global__ __launch_bounds__(256, 2)
void k_pre(const float* __restrict__ x, const u16* __restrict__ WiB,
           const float* __restrict__ ctxg, u16* __restrict__ pre2) {
    const int bid = blockIdx.x;          // stripe*32 + nc ; 512*32 blocks
    const int stripe = bid >> 5, nc = bid & 31;
    const long m0 = (long)stripe * 128;
    const int n0 = nc * 128;
    const int tid = threadIdx.x;
    const int lane = tid & 63, wid = tid >> 6;
    const int wm = wid >> 1, wn = wid & 1;          // 2x2 waves

    __shared__ u16 As[128][72];   // 128 x 64 bf16, +8 pad
    __shared__ u16 Bs[128][72];

    floatx4 acc[4][4] = {};

    const int b = (int)(m0 >> 9);                  // batch (block never straddles)
    const int row = tid >> 1, half = tid & 1;
    const float* xsrc = x + (m0 + row) * Isz + half * 32;
    const u16*   wsrc = WiB + (long)(n0 + row) * Isz + half * 32;

    for (int kc = 0; kc < Isz; kc += 64) {
        // stage A: fp32 -> bf16
        const float4* xa = (const float4*)(xsrc + kc);
        #pragma unroll
        for (int j = 0; j < 8; j++) {
            float4 v = xa[j];
            u32 lo = (u32)f2bf(v.x) | ((u32)f2bf(v.y) << 16);
            u32 hi = (u32)f2bf(v.z) | ((u32)f2bf(v.w) << 16);
            *(uint2*)&As[row][half * 32 + j * 4] = make_uint2(lo, hi);
        }
        // stage B: bf16 copy
        const uint4* wa = (const uint4*)(wsrc + kc);
        uint4* bdst = (uint4*)&Bs[row][half * 32];
        #pragma unroll
        for (int j = 0; j < 4; j++) bdst[j] = wa[j];
        __syncthreads();

        #pragma unroll
        for (int kk = 0; kk < 64; kk += 32) {
            const int qr = lane & 15;
            const int qk = kk + (lane >> 4) * 8;
            short8 af[4], bfr[4];
            #pragma unroll
            for (int i2 = 0; i2 < 4; i2++)
                af[i2] = *(const short8*)&As[wm * 64 + i2 * 16 + qr][qk];
            #pragma unroll
            for (int j2 = 0; j2 < 4; j2++)
                bfr[j2] = *(const short8*)&Bs[wn * 64 + j2 * 16 + qr][qk];
            #pragma unroll
            for (int i2 = 0; i2 < 4; i2++)
                #pragma unroll
                for (int j2 = 0; j2 < 4; j2++)
                    acc[i2][j2] = __builtin_amdgcn_mfma_f32_16x16x32_bf16(
                        af[i2], bfr[j2], acc[i2][j2], 0, 0, 0);
        }
        __syncthreads();
    }

    // epilogue: + ctxg, store bf16 into pre2 tiled layout.
    const int q4 = (lane >> 4) * 4, qc = lane & 15;
    const int g = n0 >> 10;                    // gate index (const per block)
    const int colb = g * 16 + qc;              // col within 64
    const int mb2 = b >> 5, brow = b & 31;
    const int nb_base = (n0 & 1023) >> 4;
    #pragma unroll
    for (int i2 = 0; i2 < 4; i2++) {
        #pragma unroll
        for (int j2 = 0; j2 < 4; j2++) {
            const int gc = n0 + wn * 64 + j2 * 16 + qc;
            const float cv = ctxg[(long)b * G4 + gc];
            const int nbb = nb_base + wn * 4 + j2;
            const long grow = m0 + wm * 64 + i2 * 16 + q4;
            #pragma unroll
            for (int r = 0; r < 4; r++) {
                const int tt = (int)((grow + r) & 511);
                pre2[(((long)tt * 4 + mb2) * 64 + nbb) * 2048 + brow * 64 + colb] =
                    f2bf(acc[i2][j2][r] + cv);
            }
        }
    }
}

// ---------------------------------------------------------------------------
// Persistent recurrence: 256 blocks (cooperative), block (mb,nb) owns
// batches b0..b0+31, units u0..u0+15 (x4 gates). Wave kw holds the Wh slice
// for K-quarter kw*256..+256 in 128 VGPRs. c state lives in registers.
// Per-step sync: per-mb-group 64-arrival atomic counter + agent fences.
__global__ __launch_bounds__(256, 1)
void k_rnn(const u16* __restrict__ pre2, const u16* __restrict__ WhB,
           u16* __restrict__ hT, const float* __restrict__ c0,
           float* __restrict__ out, float* __restrict__ hf,
           float* __restrict__ cf, u32* __restrict__ bar) {
    const int bid = blockIdx.x;
    const int mb = bid >> 6, nb = bid & 63;
    const int b0 = mb * 32, u0 = nb * 16;
    const int tid = threadIdx.x;
    const int lane = tid & 63, kw = tid >> 6;

    __shared__ float gpart[4][2048];   // per-wave K-partials, col-major [64][32], XOR-swizzled
    __shared__ float gact[2048];       // activated gates, same layout

    // ---- B fragments: wave kw holds rows (g*16+j) x K-quarter in registers
    short8 breg[4][8];
    {
        const int r16 = lane & 15;
        const int k8 = (lane >> 4) * 8;
        #pragma unroll
        for (int g = 0; g < 4; g++) {
            const long rowbase = (long)(g * Hsz + u0 + r16) * Hsz;
            #pragma unroll
            for (int ks = 0; ks < 8; ks++)
                breg[g][ks] = *(const short8*)&WhB[rowbase + kw * 256 + ks * 32 + k8];
        }
    }

    // ---- c state in registers (cell mapping: u=tid&15, b in {tid>>4, tid>>4+16})
    const int cu = tid & 15, cb = tid >> 4;
    float creg0 = c0[(long)(b0 + cb) * Hsz + u0 + cu];
    float creg1 = c0[(long)(b0 + cb + 16) * Hsz + u0 + cu];

    // reduce-phase mapping: col = tid&63, rows (tid>>6)*8..+8
    const int rcol = tid & 63;
    const int rrow0 = (tid >> 6) * 8;
    const int rswz = (rcol & 7) << 2;

    // A-load bases (u16 units): fragment (bt, kt) at ((bt*32+kt)*64+lane)*8
    const int baseA0 = (((mb * 2) * 32 + kw * 8) * 64 + lane) * 8;
    const int baseA1 = baseA0 + 32 * 64 * 8;   // bt+1

    const int qc = lane & 15, q4 = (lane >> 4) * 4;

    for (int t = 0; t < Tsz; t++) {
        if (t > 0) {
            if (tid == 0) {
                const int bi2 = ((t - 1) * 4 + mb) << 4;
                while (__hip_atomic_load(&bar[bi2], __ATOMIC_RELAXED,
                                         __HIP_MEMORY_SCOPE_AGENT) < 64u)
                    __builtin_amdgcn_s_sleep(2);
                __threadfence();   // acquire: invalidate stale L1/L2 before reading new h
            }
            __syncthreads();
        }

        const u16* hsrc = hT + (size_t)(t & 1) * 131072;

        // prefetch this block's pre2 region (consumed in reduce phase)
        const u16* pbase = pre2 + (((long)t * 4 + mb) * 64 + nb) * 2048;
        u16 pv[8];
        #pragma unroll
        for (int r = 0; r < 8; r++) pv[r] = pbase[(rrow0 + r) * 64 + rcol];

        // ---- MFMA: partial gates [32b x 64g] over K-quarter kw
        floatx4 acc[2][4];
        #pragma unroll
        for (int mi = 0; mi < 2; mi++)
            #pragma unroll
            for (int nj = 0; nj < 4; nj++)
                acc[mi][nj] = (floatx4){0.f, 0.f, 0.f, 0.f};

        #pragma unroll
        for (int ks = 0; ks < 8; ks++) {
            short8 a0 = *(const short8*)&hsrc[baseA0 + ks * 512];
            short8 a1 = *(const short8*)&hsrc[baseA1 + ks * 512];
            #pragma unroll
            for (int nj = 0; nj < 4; nj++) {
                acc[0][nj] = __builtin_amdgcn_mfma_f32_16x16x32_bf16(
                    a0, breg[nj][ks], acc[0][nj], 0, 0, 0);
                acc[1][nj] = __builtin_amdgcn_mfma_f32_16x16x32_bf16(
                    a1, breg[nj][ks], acc[1][nj], 0, 0, 0);
            }
        }

        // ---- write partials (col-major, XOR-swizzled for balanced bank quads)
        #pragma unroll
        for (int mi = 0; mi < 2; mi++)
            #pragma unroll
            for (int nj = 0; nj < 4; nj++) {
                const int col = nj * 16 + qc;
                const int e = (col * 32 + mi * 16 + q4) ^ ((col & 7) << 2);
                *(floatx4*)&gpart[kw][e] = acc[mi][nj];
            }
        __syncthreads();

        // ---- reduce 4 K-partials + pre, activate, stash to gact
        {
            float gs[8];
            #pragma unroll
            for (int rr = 0; rr < 8; rr++) gs[rr] = bf2f(pv[rr]);
            #pragma unroll
            for (int p = 0; p < 4; p++) {
                const int e0 = (rcol * 32 + rrow0) ^ rswz;
                const int e1 = (rcol * 32 + rrow0 + 4) ^ rswz;
                floatx4 v0 = *(const floatx4*)&gpart[p][e0];
                floatx4 v1 = *(const floatx4*)&gpart[p][e1];
                gs[0] += v0[0]; gs[1] += v0[1]; gs[2] += v0[2]; gs[3] += v0[3];
                gs[4] += v1[0]; gs[5] += v1[1]; gs[6] += v1[2]; gs[7] += v1[3];
            }
            if ((rcol >> 4) == 2) {
                #pragma unroll
                for (int rr = 0; rr < 8; rr++) gs[rr] = tanhf(gs[rr]);
            } else {
                #pragma unroll
                for (int rr = 0; rr < 8; rr++) gs[rr] = 1.f / (1.f + __expf(-gs[rr]));
            }
            floatx4 w0 = {gs[0], gs[1], gs[2], gs[3]};
            floatx4 w1 = {gs[4], gs[5], gs[6], gs[7]};
            *(floatx4*)&gact[(rcol * 32 + rrow0) ^ rswz] = w0;
            *(floatx4*)&gact[(rcol * 32 + rrow0 + 4) ^ rswz] = w1;
        }
        __syncthreads();

        // ---- cell update: thread handles (b0+cb, u0+cu) and (b0+cb+16, u0+cu)
        {
            const int swu = (cu & 7) << 2;
            const int cbase = cu * 32;          // col=g*16+cu -> elem g*512 + cu*32
            const int gb0 = cb ^ swu;
            const int gb1 = (cb + 16) ^ swu;
            const float ig0 = gact[cbase + gb0];
            const float fg0 = gact[512 + cbase + gb0];
            const float gg0 = gact[1024 + cbase + gb0];
            const float og0 = gact[1536 + cbase + gb0];
            const float ig1 = gact[cbase + gb1];
            const float fg1 = gact[512 + cbase + gb1];
            const float gg1 = gact[1024 + cbase + gb1];
            const float og1 = gact[1536 + cbase + gb1];

            creg0 = fg0 * creg0 + ig0 * gg0;
            creg1 = fg1 * creg1 + ig1 * gg1;
            const float h0v = og0 * tanhf(creg0);
            const float h1v = og1 * tanhf(creg1);

            __builtin_nontemporal_store(h0v, &out[((long)(b0 + cb) * Tsz + t) * Hsz + u0 + cu]);
            __builtin_nontemporal_store(h1v, &out[((long)(b0 + cb + 16) * Tsz + t) * Hsz + u0 + cu]);

            u16* hdst = hT + (size_t)((t + 1) & 1) * 131072;
            hdst[ht_off(b0 + cb, u0 + cu)] = f2bf(h0v);
            hdst[ht_off(b0 + cb + 16, u0 + cu)] = f2bf(h1v);

            if (t == Tsz - 1) {
                hf[(long)(b0 + cb) * Hsz + u0 + cu] = h0v;
                hf[(long)(b0 + cb + 16) * Hsz + u0 + cu] = h1v;
                cf[(long)(b0 + cb) * Hsz + u0 + cu] = creg0;
                cf[(long)(b0 + cb + 16) * Hsz + u0 + cu] = creg1;
            }
        }
        __syncthreads();   // all stores drained (vmcnt 0) before signaling

        if (tid == 0) {
            __threadfence();   // release: write back h to coherence point
            __hip_atomic_fetch_add(&bar[(t * 4 + mb) << 4], 1u,
                                   __ATOMIC_RELEASE, __HIP_MEMORY_SCOPE_AGENT);
        }
    }
}

// ---------------------------------------------------------------------------
extern "C" void kernel_launch(void* const* d_in, const int* in_sizes, int n_in,
                              void* d_out, int out_size, void* d_ws, size_t ws_size,
                              hipStream_t stream) {
    const float* x   = (const float*)d_in[0];
    const float* h0  = (const float*)d_in[1];
    const float* c0  = (const float*)d_in[2];
    const float* ctx = (const float*)d_in[3];
    const float* Wi  = (const float*)d_in[4];
    const float* bi  = (const float*)d_in[5];
    const float* Wh  = (const float*)d_in[6];
    const float* bh  = (const float*)d_in[7];
    const float* Wc  = (const float*)d_in[8];
    const float* bc  = (const float*)d_in[9];

    float* out = (float*)d_out;
    float* hf  = out + (size_t)Bsz * Tsz * Hsz;   // 67108864
    float* cf  = hf + (size_t)Bsz * Hsz;

    char* ws = (char*)d_ws;
    u16*   pre2 = (u16*)(ws);                       // 536870912 B
    u16*   WiB  = (u16*)(ws + 536870912ull);        //   8388608 B
    u16*   WhB  = (u16*)(ws + 545259520ull);        //   8388608 B
    float* ctxg = (float*)(ws + 553648128ull);      //   2097152 B
    u16*   hT   = (u16*)(ws + 555745280ull);        //    524288 B (2 states)
    u32*   bar  = (u32*)(ws + 556269568ull);        //    131072 B
    // total 556400640 B

    k_cast_w<<<16384, 256, 0, stream>>>(Wi, Wh, WiB, WhB);
    k_state<<<512, 256, 0, stream>>>(h0, hT);
    k_ctxg<<<2048, 256, 0, stream>>>(ctx, Wc, bi, bh, bc, ctxg);
    k_zero<<<128, 256, 0, stream>>>(bar);
    k_pre<<<16384, 256, 0, stream>>>(x, WiB, ctxg, pre2);

    const u16* pre2c = pre2;
    const u16* WhBc  = WhB;
    const float* c0c = c0;
    void* args[] = {(void*)&pre2c, (void*)&WhBc, (void*)&hT, (void*)&c0c,
                    (void*)&out, (void*)&hf, (void*)&cf, (void*)&bar};
    hipLaunchCooperativeKernel((void*)k_rnn, dim3(256), dim3(256), args, 0, stream);
}